// Round 4
// baseline (219.406 us; speedup 1.0000x reference)
//
#include <hip/hip_runtime.h>

// CenterLoss: y:int[16384], feat:f32[16384,128], centers:f32[100000,128]
// out = [loss (1 f32)] ++ [centers_grad (100000*128 f32)]
//
// Pipeline (4 dispatches):
//   fill d_out with 0 (zeros loss + all grad rows at fill-engine BW ~6.5 TB/s)
//   fill cnt+nocc with 0 (400 KB)
//   K1: loss (gather centers[y], block-reduce, 1 atomic/block) + histogram
//       + fixed-capacity bucket scatter + compact occupied-class list
//   K2: ONE WAVE PER OCCUPIED CLASS (~15.1k of 100k): float2 lanes cover the
//       full 512 B row; overwrite the pre-zeroed row with ratio*(ce - mean).
//       Empty classes never touched by a wave (the fill already wrote them).

#define BATCH   16384
#define FEAT    128
#define NCLASS  100000
#define LOSS_W  0.01f
#define CAP     32      // max samples/class tracked; P(count>32) ~ 1e-60 for
                        // 16384 uniform draws over 100k classes (guarded anyway)

// ---- K1: loss + histogram + bucket scatter + occ-list. ----
// One thread per (sample, float4 chunk): 16384*32 threads.
__global__ __launch_bounds__(256)
void k_loss_hist(const int* __restrict__ y,
                 const float* __restrict__ feat,
                 const float* __restrict__ centers,
                 int* __restrict__ cnt,
                 int* __restrict__ nocc,
                 int* __restrict__ occ,
                 int* __restrict__ bucket,
                 float* __restrict__ loss) {
    int t  = blockIdx.x * 256 + threadIdx.x;
    int i  = t >> 5;             // sample
    int d4 = (t & 31) << 2;      // feature offset
    int c  = y[i];

    const float4 f  = *(const float4*)(feat    + (size_t)i * FEAT + d4);
    const float4 ce = *(const float4*)(centers + (size_t)c * FEAT + d4);

    if (d4 == 0) {
        int r = atomicAdd(cnt + c, 1);
        if (r < CAP) bucket[(size_t)c * CAP + r] = i;
        if (r == 0) occ[atomicAdd(nocc, 1)] = c;   // first sample of class c
    }

    float dx = f.x - ce.x, dy = f.y - ce.y, dz = f.z - ce.z, dw = f.w - ce.w;
    float s = dx*dx + dy*dy + dz*dz + dw*dw;

    #pragma unroll
    for (int off = 32; off > 0; off >>= 1)
        s += __shfl_down(s, off, 64);

    __shared__ float smem[4];
    int lane = threadIdx.x & 63, wave = threadIdx.x >> 6;
    if (lane == 0) smem[wave] = s;
    __syncthreads();
    if (threadIdx.x == 0)
        atomicAdd(loss, LOSS_W * 0.5f * (smem[0] + smem[1] + smem[2] + smem[3]));
}

// ---- K2: one wave per occupied class; float2 lanes = full 512 B row. ----
__global__ __launch_bounds__(256)
void k_grad_occ(const float* __restrict__ centers,
                const int* __restrict__ cnt,
                const int* __restrict__ nocc,
                const int* __restrict__ occ,
                const int* __restrict__ bucket,
                const float* __restrict__ feat,
                float* __restrict__ grad) {
    int w    = (blockIdx.x * 256 + threadIdx.x) >> 6;   // wave id = occ index
    int lane = threadIdx.x & 63;
    if (w >= *nocc) return;

    int c = occ[w];
    int n = cnt[c];
    // centers row load issues early (independent of the bucket chain)
    const float2 ce = *((const float2*)(centers + (size_t)c * FEAT) + lane);

    int m = n < CAP ? n : CAP;
    float ax = 0.0f, ay = 0.0f;
    for (int k = 0; k < m; k++) {
        int i = bucket[(size_t)c * CAP + k];            // wave-broadcast load
        float2 f = *((const float2*)(feat + (size_t)i * FEAT) + lane);
        ax += f.x; ay += f.y;
    }
    float inv   = 1.0f / (float)n;
    float ratio = (float)n / (1.0f + (float)n);
    float2 o;
    o.x = ratio * (ce.x - ax * inv);
    o.y = ratio * (ce.y - ay * inv);
    *((float2*)(grad + (size_t)c * FEAT) + lane) = o;
}

extern "C" void kernel_launch(void* const* d_in, const int* in_sizes, int n_in,
                              void* d_out, int out_size, void* d_ws, size_t ws_size,
                              hipStream_t stream) {
    const int*   y       = (const int*)d_in[0];
    const float* feat    = (const float*)d_in[1];
    const float* centers = (const float*)d_in[2];

    float* loss = (float*)d_out;        // out[0]
    float* grad = (float*)d_out + 1;    // out[1:]

    int* cnt    = (int*)d_ws;           // NCLASS ints
    int* nocc   = cnt + NCLASS;         // 1 int (zeroed together with cnt)
    int* occ    = nocc + 1;             // BATCH ints
    int* bucket = occ + BATCH;          // NCLASS*CAP ints (12.8 MB)

    // Zero loss + entire grad at fill-engine bandwidth (covers empty classes).
    hipMemsetAsync(d_out, 0, (size_t)out_size * sizeof(float), stream);
    // Zero cnt and nocc in one fill.
    hipMemsetAsync(cnt, 0, (size_t)(NCLASS + 1) * sizeof(int), stream);

    // 16384*32 threads / 256 = 2048 blocks
    k_loss_hist<<<(BATCH * (FEAT / 4)) / 256, 256, 0, stream>>>(
        y, feat, centers, cnt, nocc, occ, bucket, loss);

    // Up to 16384 occupied classes; 1 wave each -> 16384/4 = 4096 blocks.
    k_grad_occ<<<BATCH / 4, 256, 0, stream>>>(
        centers, cnt, nocc, occ, bucket, feat, grad);
}

// Round 5
// 137.052 us; speedup vs baseline: 1.6009x; 1.6009x over previous
//
#include <hip/hip_runtime.h>

// CenterLoss: y:int[16384], feat:f32[16384,128], centers:f32[100000,128]
// out = [loss (1 f32)] ++ [centers_grad (100000*128 f32)]
//
// Pipeline (4 dispatches, NO same-address atomic hot spots — R4 showed ~15k
// same-address atomics cost 106us):
//   memset cnt (400 KB)
//   K1: histogram + fixed-capacity bucket scatter (16384 threads, scattered
//       int atomics only; no feat/centers reads)
//   K2: wave per 2 classes. Empty class -> write zeros (no big memset).
//       Occupied -> gather feat rows via bucket, accumulate mean AND
//       sum|f-ce|^2 (the loss) in the same pass; centers row loaded only
//       for occupied classes. Per-block loss partial -> partial[12500].
//   K3: single block reduces partial[] -> loss. No float atomics anywhere.

#define BATCH   16384
#define FEAT    128
#define NCLASS  100000
#define LOSS_W  0.01f
#define CAP     32      // max samples/class tracked; P(count>32) ~ 1e-60 for
                        // 16384 uniform draws over 100k classes (guarded anyway)
#define NPART   12500   // K2 grid size = 100000 classes / 2 per wave / 4 waves

// ---- K1: histogram + bucket. One thread per sample. ----
__global__ __launch_bounds__(256)
void k_hist(const int* __restrict__ y,
            int* __restrict__ cnt,
            int* __restrict__ bucket) {
    int i = blockIdx.x * 256 + threadIdx.x;
    int c = y[i];
    int r = atomicAdd(cnt + c, 1);          // scattered over 100k addrs: fast
    if (r < CAP) bucket[c * CAP + r] = i;
}

// ---- K2: grad + loss partials. One wave handles 2 adjacent classes
//      (32 float4 lanes each); stores form one contiguous 1 KiB run. ----
__global__ __launch_bounds__(256)
void k_grad_loss(const float* __restrict__ centers,
                 const int* __restrict__ cnt,
                 const int* __restrict__ bucket,
                 const float* __restrict__ feat,
                 float* __restrict__ grad,
                 float* __restrict__ partial) {
    int wid  = (blockIdx.x * 256 + threadIdx.x) >> 6;   // wave id: 2 classes
    int lane = threadIdx.x & 63;
    int c    = wid * 2 + (lane >> 5);                   // per-half-wave class
    int q    = lane & 31;                               // float4 index in row
    // grid exactly covers NCLASS*... wait: 12500 blocks * 4 waves * 2 = 100000
    int n = cnt[c];

    float4 ce = make_float4(0.0f, 0.0f, 0.0f, 0.0f);
    if (n > 0)                                          // skip 85% of rows
        ce = *((const float4*)(centers + (size_t)c * FEAT) + q);

    int m = n < CAP ? n : CAP;
    float4 acc = make_float4(0.0f, 0.0f, 0.0f, 0.0f);
    float ls = 0.0f;
    for (int k = 0; k < m; k++) {
        int i = bucket[c * CAP + k];                    // half-wave broadcast
        float4 f = *((const float4*)(feat + (size_t)i * FEAT) + q);
        acc.x += f.x; acc.y += f.y; acc.z += f.z; acc.w += f.w;
        float dx = f.x - ce.x, dy = f.y - ce.y;
        float dz = f.z - ce.z, dw = f.w - ce.w;
        ls += dx*dx + dy*dy + dz*dz + dw*dw;
    }

    float4 o = make_float4(0.0f, 0.0f, 0.0f, 0.0f);
    if (n > 0) {
        float inv   = 1.0f / (float)n;
        float ratio = (float)n / (1.0f + (float)n);
        o.x = ratio * (ce.x - acc.x * inv);
        o.y = ratio * (ce.y - acc.y * inv);
        o.z = ratio * (ce.z - acc.z * inv);
        o.w = ratio * (ce.w - acc.w * inv);
    }
    *((float4*)(grad + (size_t)c * FEAT) + q) = o;

    // block-reduce loss partial (no early returns above: all lanes arrive)
    #pragma unroll
    for (int off = 32; off > 0; off >>= 1)
        ls += __shfl_down(ls, off, 64);
    __shared__ float smem[4];
    if (lane == 0) smem[threadIdx.x >> 6] = ls;
    __syncthreads();
    if (threadIdx.x == 0)
        partial[blockIdx.x] = smem[0] + smem[1] + smem[2] + smem[3];
}

// ---- K3: reduce partial[NPART] -> loss (single block). ----
__global__ __launch_bounds__(256)
void k_loss_final(const float* __restrict__ partial,
                  float* __restrict__ loss) {
    float s = 0.0f;
    for (int i = threadIdx.x; i < NPART; i += 256) s += partial[i];
    #pragma unroll
    for (int off = 32; off > 0; off >>= 1)
        s += __shfl_down(s, off, 64);
    __shared__ float smem[4];
    if ((threadIdx.x & 63) == 0) smem[threadIdx.x >> 6] = s;
    __syncthreads();
    if (threadIdx.x == 0)
        *loss = LOSS_W * 0.5f * (smem[0] + smem[1] + smem[2] + smem[3]);
}

extern "C" void kernel_launch(void* const* d_in, const int* in_sizes, int n_in,
                              void* d_out, int out_size, void* d_ws, size_t ws_size,
                              hipStream_t stream) {
    const int*   y       = (const int*)d_in[0];
    const float* feat    = (const float*)d_in[1];
    const float* centers = (const float*)d_in[2];

    float* loss = (float*)d_out;        // out[0]
    float* grad = (float*)d_out + 1;    // out[1:]

    int*   cnt     = (int*)d_ws;            // NCLASS ints
    int*   bucket  = cnt + NCLASS;          // NCLASS*CAP ints (12.8 MB)
    float* partial = (float*)(bucket + (size_t)NCLASS * CAP);  // NPART floats

    hipMemsetAsync(cnt, 0, (size_t)NCLASS * sizeof(int), stream);

    // 16384 threads = 64 blocks
    k_hist<<<BATCH / 256, 256, 0, stream>>>(y, cnt, bucket);

    // 100000 classes / 2 per wave / 4 waves per block = 12500 blocks
    k_grad_loss<<<NPART, 256, 0, stream>>>(
        centers, cnt, bucket, feat, grad, partial);

    k_loss_final<<<1, 256, 0, stream>>>(partial, loss);
}

// Round 7
// 125.983 us; speedup vs baseline: 1.7416x; 1.0879x over previous
//
#include <hip/hip_runtime.h>

// CenterLoss: y:int[16384], feat:f32[16384,128], centers:f32[100000,128]
// out = [loss (1 f32)] ++ [centers_grad (100000*128 f32)]
//
// Pipeline (4 dispatches):
//   memset cnt (400 KB)
//   K1: histogram + fixed-capacity bucket scatter (16384 threads)
//   K2: wave per 2 classes. Empty -> zeros; occupied -> gather feat via
//       bucket, accumulate mean AND sum|f-ce|^2 in one pass. Non-temporal
//       stores (grad is write-once/read-never) + NT loads (read-once).
//       Per-block loss partial -> partial[12500].
//   K3: single block reduces partial[] -> loss (float4 grid-stride).
//
// Notes from earlier rounds:
//   - same-address global atomics ~5.5ns/op serialized (R4: 16.4k ops = +90us)
//     => no atomic loss accumulation, no last-block ticket merge.
//   - harness poison/restore (~110us of the window) is a fixed floor; our
//     dispatches don't appear in the top-5.
//   - __builtin_nontemporal_* needs a clang ext-vector type, not HIP float4.

#define BATCH   16384
#define FEAT    128
#define NCLASS  100000
#define LOSS_W  0.01f
#define CAP     32      // P(count>32) ~ 1e-60 for 16384 draws over 100k classes
#define NPART   12500   // K2 grid = 100000 / (2 classes/wave * 4 waves)

typedef float v4f __attribute__((ext_vector_type(4)));

// ---- K1: histogram + bucket. One thread per sample. ----
__global__ __launch_bounds__(256)
void k_hist(const int* __restrict__ y,
            int* __restrict__ cnt,
            int* __restrict__ bucket) {
    int i = blockIdx.x * 256 + threadIdx.x;
    int c = y[i];
    int r = atomicAdd(cnt + c, 1);          // scattered over 100k addrs: fast
    if (r < CAP) bucket[c * CAP + r] = i;
}

// ---- K2: grad + loss partials. One wave = 2 adjacent classes
//      (32 float4 lanes each); stores form one contiguous 1 KiB run. ----
__global__ __launch_bounds__(256)
void k_grad_loss(const float* __restrict__ centers,
                 const int* __restrict__ cnt,
                 const int* __restrict__ bucket,
                 const float* __restrict__ feat,
                 float* __restrict__ grad,
                 float* __restrict__ partial) {
    int wid  = (blockIdx.x * 256 + threadIdx.x) >> 6;   // wave id: 2 classes
    int lane = threadIdx.x & 63;
    int c    = wid * 2 + (lane >> 5);                   // per-half-wave class
    int q    = lane & 31;                               // float4 index in row
    int n = cnt[c];

    v4f ce = (v4f)(0.0f);
    if (n > 0)                                          // skip ~85% of rows
        ce = __builtin_nontemporal_load(
                 (const v4f*)(centers + (size_t)c * FEAT) + q);

    int m = n < CAP ? n : CAP;
    v4f acc = (v4f)(0.0f);
    float ls = 0.0f;
    for (int k = 0; k < m; k++) {
        int i = bucket[c * CAP + k];                    // half-wave broadcast
        v4f f = __builtin_nontemporal_load(
                    (const v4f*)(feat + (size_t)i * FEAT) + q);
        acc += f;
        v4f d = f - ce;
        ls += d.x*d.x + d.y*d.y + d.z*d.z + d.w*d.w;
    }

    v4f o = (v4f)(0.0f);
    if (n > 0) {
        float inv   = 1.0f / (float)n;
        float ratio = (float)n / (1.0f + (float)n);
        o = ratio * (ce - acc * inv);
    }
    __builtin_nontemporal_store(o, (v4f*)(grad + (size_t)c * FEAT) + q);

    // block-reduce loss partial (all lanes reach here: no early returns)
    #pragma unroll
    for (int off = 32; off > 0; off >>= 1)
        ls += __shfl_down(ls, off, 64);
    __shared__ float smem[4];
    if (lane == 0) smem[threadIdx.x >> 6] = ls;
    __syncthreads();
    if (threadIdx.x == 0)
        partial[blockIdx.x] = smem[0] + smem[1] + smem[2] + smem[3];
}

// ---- K3: reduce partial[NPART] -> loss (single block, float4 loads). ----
__global__ __launch_bounds__(256)
void k_loss_final(const float* __restrict__ partial,
                  float* __restrict__ loss) {
    float s = 0.0f;
    const v4f* p4 = (const v4f*)partial;                // NPART = 12500 = 3125*4
    for (int i = threadIdx.x; i < NPART / 4; i += 256) {
        v4f v = p4[i];
        s += v.x + v.y + v.z + v.w;
    }
    #pragma unroll
    for (int off = 32; off > 0; off >>= 1)
        s += __shfl_down(s, off, 64);
    __shared__ float smem[4];
    if ((threadIdx.x & 63) == 0) smem[threadIdx.x >> 6] = s;
    __syncthreads();
    if (threadIdx.x == 0)
        *loss = LOSS_W * 0.5f * (smem[0] + smem[1] + smem[2] + smem[3]);
}

extern "C" void kernel_launch(void* const* d_in, const int* in_sizes, int n_in,
                              void* d_out, int out_size, void* d_ws, size_t ws_size,
                              hipStream_t stream) {
    const int*   y       = (const int*)d_in[0];
    const float* feat    = (const float*)d_in[1];
    const float* centers = (const float*)d_in[2];

    float* loss = (float*)d_out;        // out[0]
    float* grad = (float*)d_out + 1;    // out[1:]

    int*   cnt     = (int*)d_ws;            // NCLASS ints
    int*   bucket  = cnt + NCLASS;          // NCLASS*CAP ints (12.8 MB)
    float* partial = (float*)(bucket + (size_t)NCLASS * CAP);  // NPART floats

    (void)hipMemsetAsync(cnt, 0, (size_t)NCLASS * sizeof(int), stream);

    // 16384 threads = 64 blocks
    k_hist<<<BATCH / 256, 256, 0, stream>>>(y, cnt, bucket);

    // 100000 classes / 2 per wave / 4 waves per block = 12500 blocks
    k_grad_loss<<<NPART, 256, 0, stream>>>(
        centers, cnt, bucket, feat, grad, partial);

    k_loss_final<<<1, 256, 0, stream>>>(partial, loss);
}